// Round 5
// baseline (422.168 us; speedup 1.0000x reference)
//
#include <hip/hip_runtime.h>
#include <math.h>

#define HDIM 1024
#define FDIM 2048   // 2H
#define NEXP 8
#define MTOK 16384  // 8*2048 tokens
#define NSLC 32     // partial-logit slices: 16 n-blocks x 2 wn-waves

typedef __attribute__((ext_vector_type(8))) short bf16x8;   // 8 bf16 = 4 VGPRs
typedef __attribute__((ext_vector_type(4))) float f32x4;

__device__ inline unsigned short f2bf_rne(float f) {
    unsigned int u = __float_as_uint(f);
    u = (u + 0x7FFFu + ((u >> 16) & 1u)) >> 16;
    return (unsigned short)u;
}
__device__ inline float bf2f(unsigned short h) {
    unsigned int u = ((unsigned int)h) << 16;
    return __uint_as_float(u);
}

// --- Kernel A: x fp32 -> FRAGMENT-MAJOR split bf16 af (r0 verbatim) ---
__global__ __launch_bounds__(256) void cvt_x(const float* __restrict__ x,
                                             unsigned short* __restrict__ af)
{
    __shared__ unsigned short hs[16384];  // 32 KB  [kb][m][q][j]
    __shared__ unsigned short ls[16384];  // 32 KB
    const int mt = blockIdx.x;            // 0..1023
    const float* src = x + (size_t)mt * 16384;
    const int m = threadIdx.x & 15;
    const int kseg = threadIdx.x >> 4;    // 0..15

    #pragma unroll
    for (int c = 0; c < 8; c++) {
        int k = c * 128 + kseg * 8;
        float v[8];
        *(float4*)(v)     = *(const float4*)(src + m * 1024 + k);
        *(float4*)(v + 4) = *(const float4*)(src + m * 1024 + k + 4);
        union { unsigned short u[8]; uint4 q; } oh, ol;
        #pragma unroll
        for (int j = 0; j < 8; j++) {
            unsigned short h = f2bf_rne(v[j]);
            oh.u[j] = h;
            ol.u[j] = f2bf_rne(v[j] - bf2f(h));
        }
        int kb = k >> 5, q = (k >> 3) & 3;
        int o = kb * 512 + m * 32 + q * 8;
        *(uint4*)(hs + o) = oh.q;
        *(uint4*)(ls + o) = ol.q;
    }
    __syncthreads();
    unsigned short* dst = af + (size_t)mt * 32768;
    #pragma unroll
    for (int c = 0; c < 16; c++) {
        int f = c * 2048 + threadIdx.x * 8;       // flat out index (shorts)
        int kb = f >> 10, half = (f >> 9) & 1, idx = f & 511;
        int q = idx >> 7, mm = (idx >> 3) & 15;
        const unsigned short* s = (half ? ls : hs) + kb * 512 + mm * 32 + q * 8;
        *(uint4*)(dst + f) = *(const uint4*)s;
    }
}

// --- Kernel B: w1 [K][N] fp32 -> FRAGMENT-MAJOR split bf16 wf (r0 verbatim) ---
__global__ __launch_bounds__(256) void cvt_w1f(const float* __restrict__ w1,
                                               unsigned short* __restrict__ wf)
{
    __shared__ float t[32][33];
    int n0 = blockIdx.x * 32;   // over FDIM
    int k0 = blockIdx.y * 32;   // over HDIM
    int lx = threadIdx.x & 31, ly = threadIdx.x >> 5;  // 32 x 8
    #pragma unroll
    for (int r = 0; r < 32; r += 8)
        t[ly + r][lx] = w1[(size_t)(k0 + ly + r) * FDIM + n0 + lx];
    __syncthreads();
    #pragma unroll
    for (int r = 0; r < 32; r += 8) {
        float v = t[lx][ly + r];
        unsigned short h = f2bf_rne(v);
        unsigned short l = f2bf_rne(v - bf2f(h));
        int n = n0 + ly + r, k = k0 + lx;
        size_t base = (size_t)((n >> 4) * 32 + (k >> 5)) * 1024;
        int lj = (((k >> 3) & 3) * 16 + (n & 15)) * 8 + (k & 7);
        wf[base + lj] = h;
        wf[base + 512 + lj] = l;
    }
}

// --- Kernel C: r0 structure (global-fed, no LDS/barriers), wave tile 128x64. ---
// bytes/MFMA 341 -> 250 (the measured limiter is L1/L2 delivery). Block tile
// 256x128, 4 waves (2 wm x 2 wn), each wave 8 mt x 4 nt. acc 128 + B dbuf 64 +
// A pair ping-pong 32 + addr ~= 245 regs @ 2 waves/SIMD (launch_bounds(256,2),
// same occupancy as r0 -> no spill cliff; WRITE_SIZE is the tripwire).
// A pairs pipeline within kb (next pair's loads under current pair's 24-MFMA
// burst); B double-buffers across kb. Per-acc chain hh->hl->lh over kb 0..31
// with identical operands -> bitwise-identical numerics.
#define LOADB(BH, BL, tt) do { \
    _Pragma("unroll") \
    for (int j_ = 0; j_ < 4; j_++) { \
        const unsigned short* p_ = bbase + (size_t)j_ * 32768 + (size_t)(tt) * 1024; \
        BH[j_] = *(const bf16x8*)(p_); \
        BL[j_] = *(const bf16x8*)(p_ + 512); \
    } } while (0)

#define LOADA(AH, AL, ip, tt) do { \
    _Pragma("unroll") \
    for (int k_ = 0; k_ < 2; k_++) { \
        const unsigned short* p_ = abase + (size_t)((ip) * 2 + k_) * 32768 + (size_t)(tt) * 1024; \
        AH[k_] = *(const bf16x8*)(p_); \
        AL[k_] = *(const bf16x8*)(p_ + 512); \
    } } while (0)

#define MFMA_PAIR(AH, AL, BH, BL, ip) do { \
    _Pragma("unroll") \
    for (int k_ = 0; k_ < 2; k_++) \
        _Pragma("unroll") \
        for (int j_ = 0; j_ < 4; j_++) { \
            f32x4 a_ = acc[(ip) * 2 + k_][j_]; \
            a_ = __builtin_amdgcn_mfma_f32_16x16x32_bf16(AH[k_], BH[j_], a_, 0, 0, 0); \
            a_ = __builtin_amdgcn_mfma_f32_16x16x32_bf16(AH[k_], BL[j_], a_, 0, 0, 0); \
            a_ = __builtin_amdgcn_mfma_f32_16x16x32_bf16(AL[k_], BH[j_], a_, 0, 0, 0); \
            acc[(ip) * 2 + k_][j_] = a_; \
        } } while (0)

__global__ __launch_bounds__(256, 2) void gemm1_mfma(
    const unsigned short* __restrict__ af, const unsigned short* __restrict__ wf,
    const float* __restrict__ b1, const float* __restrict__ w2,
    float* __restrict__ part)
{
    const int tid  = threadIdx.x;
    const int lane = tid & 63;
    const int l15  = lane & 15;
    const int q    = lane >> 4;
    const int wave = tid >> 6;      // 0..3
    const int wm   = wave & 1;      // 128-row half
    const int wn   = wave >> 1;     // 64-col half

    // XCD-aware swizzle (bijective: 1024 = 8 xcd x 8 bm x 16 bn). bn walks
    // fastest so each XCD's 1 MB A-tile is L2-reused across 16 bn blocks.
    const int id  = blockIdx.x;     // 0..1023
    const int xcd = id & 7, seq = id >> 3;   // seq 0..127
    const int bn  = seq & 15;                // 0..15
    const int bm  = xcd * 8 + (seq >> 4);    // 0..63
    const int m0  = bm * 256, n0 = bn * 128;

    // frag bases: A frag i at abase + i*32768 + kb*1024 (+512 for l)
    const unsigned short* abase = af + (size_t)(bm * 16 + wm * 8) * 32768 + lane * 8;
    const unsigned short* bbase = wf + (size_t)(bn * 8 + wn * 4) * 32768 + lane * 8;

    f32x4 acc[8][4];
    #pragma unroll
    for (int i = 0; i < 8; i++)
        #pragma unroll
        for (int j = 0; j < 4; j++) acc[i][j] = (f32x4){0.f, 0.f, 0.f, 0.f};

    bf16x8 BhA[4], BlA[4], BhB[4], BlB[4];   // B ping-pong (across kb)
    bf16x8 AhX[2], AlX[2], AhY[2], AlY[2];   // A pair ping-pong (within kb)

    LOADB(BhA, BlA, 0);
    LOADA(AhX, AlX, 0, 0);

    #pragma unroll 1
    for (int t = 0; t < 32; t += 2) {
        // ---- kb t (B set A) ----
        LOADA(AhY, AlY, 1, t);
        MFMA_PAIR(AhX, AlX, BhA, BlA, 0);
        LOADA(AhX, AlX, 2, t);
        MFMA_PAIR(AhY, AlY, BhA, BlA, 1);
        LOADA(AhY, AlY, 3, t);
        MFMA_PAIR(AhX, AlX, BhA, BlA, 2);
        LOADB(BhB, BlB, t + 1);
        LOADA(AhX, AlX, 0, t + 1);
        MFMA_PAIR(AhY, AlY, BhA, BlA, 3);
        // ---- kb t+1 (B set B) ----
        LOADA(AhY, AlY, 1, t + 1);
        MFMA_PAIR(AhX, AlX, BhB, BlB, 0);
        LOADA(AhX, AlX, 2, t + 1);
        MFMA_PAIR(AhY, AlY, BhB, BlB, 1);
        LOADA(AhY, AlY, 3, t + 1);
        MFMA_PAIR(AhX, AlX, BhB, BlB, 2);
        if (t + 2 < 32) {
            LOADB(BhA, BlA, t + 2);
            LOADA(AhX, AlX, 0, t + 2);
        }
        MFMA_PAIR(AhY, AlY, BhB, BlB, 3);
    }

    // --- epilogue: bias + exact GELU (C/D: col=lane&15 -> n, row=q*4+r -> m) ---
    #pragma unroll
    for (int j = 0; j < 4; j++) {
        int n = n0 + wn * 64 + j * 16 + l15;
        float bb = b1[n];
        #pragma unroll
        for (int i = 0; i < 8; i++)
            #pragma unroll
            for (int r = 0; r < 4; r++) {
                float v = acc[i][j][r] + bb;
                acc[i][j][r] = 0.5f * v * (1.0f + erff(v * 0.70710678118654752f));
            }
    }

    // w2 rows for this lane's 4 n-columns
    float w2r[4][8];
    #pragma unroll
    for (int j = 0; j < 4; j++) {
        const float4* p = (const float4*)(w2 + (size_t)(n0 + wn * 64 + j * 16 + l15) * NEXP);
        float4 u = p[0], v = p[1];
        w2r[j][0] = u.x; w2r[j][1] = u.y; w2r[j][2] = u.z; w2r[j][3] = u.w;
        w2r[j][4] = v.x; w2r[j][5] = v.y; w2r[j][6] = v.z; w2r[j][7] = v.w;
    }

    const int sl = bn * 2 + wn;  // partial slice: covers n in [sl*64, sl*64+64)
    #pragma unroll
    for (int e = 0; e < NEXP; e++) {
        float p[8][4];
        #pragma unroll
        for (int i = 0; i < 8; i++)
            #pragma unroll
            for (int r = 0; r < 4; r++) {
                float s = 0.f;
                #pragma unroll
                for (int j = 0; j < 4; j++) s += acc[i][j][r] * w2r[j][e];
                p[i][r] = s;
            }
        #pragma unroll
        for (int off = 1; off < 16; off <<= 1)
            #pragma unroll
            for (int i = 0; i < 8; i++)
                #pragma unroll
                for (int r = 0; r < 4; r++)
                    p[i][r] += __shfl_xor(p[i][r], off);
        if (l15 == 0) {
            #pragma unroll
            for (int i = 0; i < 8; i++)
                #pragma unroll
                for (int r = 0; r < 4; r++) {
                    int m = m0 + wm * 128 + i * 16 + q * 4 + r;
                    part[(size_t)sl * (MTOK * NEXP) + (size_t)m * NEXP + e] = p[i][r];
                }
        }
    }
}

// --- Kernel 2: deterministic sum of 32 slices -> logits, top-2, softmax ---
__global__ __launch_bounds__(256) void router_topk(
    const float* __restrict__ part, const float* __restrict__ b2,
    float* __restrict__ out, float* __restrict__ gu, int* __restrict__ gc)
{
    const int t = blockIdx.x * 256 + threadIdx.x;

    float logit[8];
    #pragma unroll
    for (int e = 0; e < 8; e++) logit[e] = b2[e];
    #pragma unroll
    for (int j = 0; j < NSLC; j++) {
        const float4* p4 = (const float4*)(part + (size_t)j * (MTOK * NEXP) + (size_t)t * NEXP);
        float4 u = p4[0], v = p4[1];
        logit[0] += u.x; logit[1] += u.y; logit[2] += u.z; logit[3] += u.w;
        logit[4] += v.x; logit[5] += v.y; logit[6] += v.z; logit[7] += v.w;
    }

    int i1 = 0; float v1 = logit[0];
    #pragma unroll
    for (int e = 1; e < 8; e++) { if (logit[e] > v1) { v1 = logit[e]; i1 = e; } }
    int i2 = -1; float v2 = -INFINITY;
    #pragma unroll
    for (int e = 0; e < 8; e++) {
        if (e != i1 && logit[e] > v2) { v2 = logit[e]; i2 = e; }
    }
    float ex = expf(v2 - v1);
    float inv = 1.0f / (1.0f + ex);
    float wa = inv, wb = ex * inv;

    float4* o = (float4*)(out + (size_t)t * NEXP);
    o[0] = make_float4(logit[0], logit[1], logit[2], logit[3]);
    o[1] = make_float4(logit[4], logit[5], logit[6], logit[7]);

    float mk[8];
    #pragma unroll
    for (int e = 0; e < 8; e++) mk[e] = 0.0f;
    mk[i1] = wa; mk[i2] = wb;
    float4* om = (float4*)(out + (size_t)(MTOK * NEXP) + (size_t)t * NEXP);
    om[0] = make_float4(mk[0], mk[1], mk[2], mk[3]);
    om[1] = make_float4(mk[4], mk[5], mk[6], mk[7]);

    __shared__ float us[8];
    __shared__ int cs;
    if (threadIdx.x < 8) us[threadIdx.x] = 0.0f;
    if (threadIdx.x == 0) cs = 0;
    __syncthreads();
    atomicAdd(&us[i1], wa);
    atomicAdd(&us[i2], wb);
    int cnt = (wa > 0.0f ? 1 : 0) + (wb > 0.0f ? 1 : 0);
    atomicAdd(&cs, cnt);
    __syncthreads();
    if (threadIdx.x < 8) atomicAdd(&gu[threadIdx.x], us[threadIdx.x]);
    if (threadIdx.x == 0) atomicAdd(gc, cs);
}

// --- Kernel 3: finalize losses + normalized usage ---
__global__ void router_final(const float* __restrict__ gu, const int* __restrict__ gc,
                             float* __restrict__ out)
{
    if (blockIdx.x == 0 && threadIdx.x == 0) {
        float u[8]; float tot = 0.0f;
        for (int e = 0; e < 8; e++) { u[e] = gu[e]; tot += u[e]; }
        float lb = 0.0f;
        for (int e = 0; e < 8; e++) {
            float un = u[e] / tot;
            out[2 * MTOK * NEXP + 1 + e] = un;
            float d = un - 0.125f;
            lb += d * d;
        }
        lb *= (1.0f / 8.0f);
        float sp = ((float)(*gc) / (float)MTOK) * 0.5f;
        out[2 * MTOK * NEXP] = lb + 0.1f * sp;
    }
}

extern "C" void kernel_launch(void* const* d_in, const int* in_sizes, int n_in,
                              void* d_out, int out_size, void* d_ws, size_t ws_size,
                              hipStream_t stream) {
    const float* x  = (const float*)d_in[0];
    const float* w1 = (const float*)d_in[1];
    const float* b1 = (const float*)d_in[2];
    const float* w2 = (const float*)d_in[3];
    const float* b2 = (const float*)d_in[4];
    float* out = (float*)d_out;

    unsigned short* af = (unsigned short*)d_ws;            // 1024*32768*2 B = 64 MiB
    unsigned short* wf = af + (size_t)1024 * 32768;        // 8 MiB
    float* part = (float*)(wf + (size_t)128 * 32 * 1024);  // 16 MiB
    float* gu = part + (size_t)NSLC * MTOK * NEXP;
    int* gc = (int*)(gu + 8);

    hipMemsetAsync(gu, 0, 64, stream);

    cvt_x<<<1024, 256, 0, stream>>>(x, af);
    cvt_w1f<<<dim3(FDIM / 32, HDIM / 32), 256, 0, stream>>>(w1, wf);
    gemm1_mfma<<<1024, 256, 0, stream>>>(af, wf, b1, w2, part);
    router_topk<<<MTOK / 256, 256, 0, stream>>>(part, b2, out, gu, gc);
    router_final<<<1, 64, 0, stream>>>(gu, gc, out);
}

// Round 6
// 361.707 us; speedup vs baseline: 1.1672x; 1.1672x over previous
//
#include <hip/hip_runtime.h>
#include <math.h>

#define HDIM 1024
#define FDIM 2048   // 2H
#define NEXP 8
#define MTOK 16384  // 8*2048 tokens
#define NSLC 32     // partial-logit slices: 16 bn-blocks x 2 wn-waves
#define LDSB 24576              // shorts per LDS buffer (48 KB): 24 frags x 1024
#define LDS_BYTES (3 * 49152)   // triple buffer, 144 KB

typedef __attribute__((ext_vector_type(8))) short bf16x8;   // 8 bf16 = 4 VGPRs
typedef __attribute__((ext_vector_type(4))) float f32x4;

__device__ inline unsigned short f2bf_rne(float f) {
    unsigned int u = __float_as_uint(f);
    u = (u + 0x7FFFu + ((u >> 16) & 1u)) >> 16;
    return (unsigned short)u;
}
__device__ inline float bf2f(unsigned short h) {
    unsigned int u = ((unsigned int)h) << 16;
    return __uint_as_float(u);
}

// --- Kernel A: x fp32 -> FRAGMENT-MAJOR split bf16 af (unchanged) ---
__global__ __launch_bounds__(256) void cvt_x(const float* __restrict__ x,
                                             unsigned short* __restrict__ af)
{
    __shared__ unsigned short hs[16384];  // 32 KB  [kb][m][q][j]
    __shared__ unsigned short ls[16384];  // 32 KB
    const int mt = blockIdx.x;            // 0..1023
    const float* src = x + (size_t)mt * 16384;
    const int m = threadIdx.x & 15;
    const int kseg = threadIdx.x >> 4;    // 0..15

    #pragma unroll
    for (int c = 0; c < 8; c++) {
        int k = c * 128 + kseg * 8;
        float v[8];
        *(float4*)(v)     = *(const float4*)(src + m * 1024 + k);
        *(float4*)(v + 4) = *(const float4*)(src + m * 1024 + k + 4);
        union { unsigned short u[8]; uint4 q; } oh, ol;
        #pragma unroll
        for (int j = 0; j < 8; j++) {
            unsigned short h = f2bf_rne(v[j]);
            oh.u[j] = h;
            ol.u[j] = f2bf_rne(v[j] - bf2f(h));
        }
        int kb = k >> 5, q = (k >> 3) & 3;
        int o = kb * 512 + m * 32 + q * 8;
        *(uint4*)(hs + o) = oh.q;
        *(uint4*)(ls + o) = ol.q;
    }
    __syncthreads();
    unsigned short* dst = af + (size_t)mt * 32768;
    #pragma unroll
    for (int c = 0; c < 16; c++) {
        int f = c * 2048 + threadIdx.x * 8;       // flat out index (shorts)
        int kb = f >> 10, half = (f >> 9) & 1, idx = f & 511;
        int q = idx >> 7, mm = (idx >> 3) & 15;
        const unsigned short* s = (half ? ls : hs) + kb * 512 + mm * 32 + q * 8;
        *(uint4*)(dst + f) = *(const uint4*)s;
    }
}

// --- Kernel B: w1 [K][N] fp32 -> FRAGMENT-MAJOR split bf16 wf (unchanged) ---
__global__ __launch_bounds__(256) void cvt_w1f(const float* __restrict__ w1,
                                               unsigned short* __restrict__ wf)
{
    __shared__ float t[32][33];
    int n0 = blockIdx.x * 32;   // over FDIM
    int k0 = blockIdx.y * 32;   // over HDIM
    int lx = threadIdx.x & 31, ly = threadIdx.x >> 5;  // 32 x 8
    #pragma unroll
    for (int r = 0; r < 32; r += 8)
        t[ly + r][lx] = w1[(size_t)(k0 + ly + r) * FDIM + n0 + lx];
    __syncthreads();
    #pragma unroll
    for (int r = 0; r < 32; r += 8) {
        float v = t[lx][ly + r];
        unsigned short h = f2bf_rne(v);
        unsigned short l = f2bf_rne(v - bf2f(h));
        int n = n0 + ly + r, k = k0 + lx;
        size_t base = (size_t)((n >> 4) * 32 + (k >> 5)) * 1024;
        int lj = (((k >> 3) & 3) * 16 + (n & 15)) * 8 + (k & 7);
        wf[base + lj] = h;
        wf[base + 512 + lj] = l;
    }
}

// --- Kernel C: LDS triple-buffer, 3 FAT phases/kb (hh | hl | lh), 4 barriers/kb.
// r2 resequenced: phase p = {ds_reads for p (before barrier, overlaps other
// waves' MFMAs); [ph1 only: 6-gload stage burst for kb t+2]; barrier;
// lgkmcnt(0)+sched_barrier; setprio(1); 16 MFMAs; setprio(0)}. Boundary:
// vmcnt(6) counted (never 0 until tail) + barrier. Stage safety: kb reads
// complete at ph3's lgkmcnt(0) < boundary barrier < next stage into that
// buffer. Per-acc chain hh->hl->lh per kb, kb ascending -> bitwise-identical.
#define GLDX4(gp, lofs) __builtin_amdgcn_global_load_lds( \
    (const __attribute__((address_space(1))) unsigned int*)(uintptr_t)(gp), \
    (__attribute__((address_space(3))) unsigned int*)(unsigned int)(uintptr_t)(smem + (lofs)), \
    16, 0, 0)

__global__ __launch_bounds__(512, 2) void gemm1_mfma(
    const unsigned short* __restrict__ af, const unsigned short* __restrict__ wf,
    const float* __restrict__ b1, const float* __restrict__ w2,
    float* __restrict__ part)
{
    extern __shared__ unsigned short smem[];
    const int tid  = threadIdx.x;
    const int lane = tid & 63;
    const int l15  = lane & 15;
    const int q    = lane >> 4;
    const int wave = tid >> 6;      // 0..7
    const int wm   = wave >> 1;     // 0..3 rows (64 each)
    const int wn   = wave & 1;      // 0..1 cols (64 each)

    // XCD-aware swizzle (bijective: 1024 = 8 xcd x 8 bm x 16 bn), bn fastest.
    const int id  = blockIdx.x;
    const int xcd = id & 7, seq = id >> 3;       // seq 0..127
    const int bn  = seq & 15;                    // 128-wide N tile
    const int bm  = xcd * 8 + (seq >> 4);        // 256-wide M tile
    const int m0  = bm * 256, n0g = bn * 128;

    // staging descriptors: this wave's 6 chunks (chunk = 1 KB = half fragment)
    const unsigned short* gb[6];
    int lo[6];
    #pragma unroll
    for (int s = 0; s < 6; s++) {
        int c = wave * 6 + s;
        int f = c >> 1, half = c & 1;            // f: 0..15 = A mt, 16..23 = B nt
        const unsigned short* base = (f < 16)
            ? af + (size_t)(bm * 16 + f) * 32768
            : wf + (size_t)(bn * 8 + (f - 16)) * 32768;
        gb[s] = base + half * 512 + lane * 8;    // per-lane global src
        lo[s] = f * 1024 + half * 512;           // wave-uniform LDS dest base
    }

    f32x4 acc[4][4];
    #pragma unroll
    for (int i = 0; i < 4; i++)
        #pragma unroll
        for (int j = 0; j < 4; j++) acc[i][j] = (f32x4){0.f, 0.f, 0.f, 0.f};

    // prologue: stage kb=0 -> buf0, kb=1 -> buf1; wait kb0 (6 of kb1 in
    // flight), publish via barrier.
    #pragma unroll
    for (int s = 0; s < 6; s++) GLDX4(gb[s], lo[s]);
    #pragma unroll
    for (int s = 0; s < 6; s++) GLDX4(gb[s] + 1024, LDSB + lo[s]);
    asm volatile("s_waitcnt vmcnt(6)\n\ts_barrier" ::: "memory");

    int bo = 0;                                   // buffer holding kb = t
    #pragma unroll 1
    for (int t = 0; t < 32; t++) {
        int bi = bo + 2 * LDSB; if (bi >= 3 * LDSB) bi -= 3 * LDSB;
        const unsigned short* sb = smem + bo;
        bf16x8 Ah[4], Bh[4], Al[4], Bl[4];

        // ---- phase 1: reads Ah,Bh; stage burst (t+2); 16x hh ----
        #pragma unroll
        for (int i = 0; i < 4; i++)
            Ah[i] = *(const bf16x8*)(sb + (wm * 4 + i) * 1024 + lane * 8);
        #pragma unroll
        for (int j = 0; j < 4; j++)
            Bh[j] = *(const bf16x8*)(sb + (16 + wn * 4 + j) * 1024 + lane * 8);
        if (t + 2 < 32) {
            const size_t goff = (size_t)(t + 2) * 1024;
            #pragma unroll
            for (int s = 0; s < 6; s++) GLDX4(gb[s] + goff, bi + lo[s]);
        }
        __builtin_amdgcn_s_barrier();
        asm volatile("s_waitcnt lgkmcnt(0)" ::: "memory");
        __builtin_amdgcn_sched_barrier(0);
        __builtin_amdgcn_s_setprio(1);
        #pragma unroll
        for (int i = 0; i < 4; i++)
            #pragma unroll
            for (int j = 0; j < 4; j++)
                acc[i][j] = __builtin_amdgcn_mfma_f32_16x16x32_bf16(
                    Ah[i], Bh[j], acc[i][j], 0, 0, 0);
        __builtin_amdgcn_s_setprio(0);
        __builtin_amdgcn_sched_barrier(0);

        // ---- phase 2: reads Bl; 16x hl ----
        #pragma unroll
        for (int j = 0; j < 4; j++)
            Bl[j] = *(const bf16x8*)(sb + (16 + wn * 4 + j) * 1024 + 512 + lane * 8);
        __builtin_amdgcn_s_barrier();
        asm volatile("s_waitcnt lgkmcnt(0)" ::: "memory");
        __builtin_amdgcn_sched_barrier(0);
        __builtin_amdgcn_s_setprio(1);
        #pragma unroll
        for (int i = 0; i < 4; i++)
            #pragma unroll
            for (int j = 0; j < 4; j++)
                acc[i][j] = __builtin_amdgcn_mfma_f32_16x16x32_bf16(
                    Ah[i], Bl[j], acc[i][j], 0, 0, 0);
        __builtin_amdgcn_s_setprio(0);
        __builtin_amdgcn_sched_barrier(0);

        // ---- phase 3: reads Al; 16x lh ----
        #pragma unroll
        for (int i = 0; i < 4; i++)
            Al[i] = *(const bf16x8*)(sb + (wm * 4 + i) * 1024 + 512 + lane * 8);
        __builtin_amdgcn_s_barrier();
        asm volatile("s_waitcnt lgkmcnt(0)" ::: "memory");
        __builtin_amdgcn_sched_barrier(0);
        __builtin_amdgcn_s_setprio(1);
        #pragma unroll
        for (int i = 0; i < 4; i++)
            #pragma unroll
            for (int j = 0; j < 4; j++)
                acc[i][j] = __builtin_amdgcn_mfma_f32_16x16x32_bf16(
                    Al[i], Bh[j], acc[i][j], 0, 0, 0);
        __builtin_amdgcn_s_setprio(0);
        __builtin_amdgcn_sched_barrier(0);

        // ---- kb boundary: publish t+1's buffer (counted vmcnt) ----
        bo += LDSB; if (bo >= 3 * LDSB) bo -= 3 * LDSB;
        if (t < 30)       asm volatile("s_waitcnt vmcnt(6)\n\ts_barrier" ::: "memory");
        else if (t == 30) asm volatile("s_waitcnt vmcnt(0)\n\ts_barrier" ::: "memory");
        // t == 31: epilogue is register/global only.
    }

    // --- epilogue: bias + exact GELU (C/D: col=lane&15 -> n, row=q*4+r -> m) ---
    #pragma unroll
    for (int j = 0; j < 4; j++) {
        int n = n0g + wn * 64 + j * 16 + l15;
        float bb = b1[n];
        #pragma unroll
        for (int i = 0; i < 4; i++)
            #pragma unroll
            for (int r = 0; r < 4; r++) {
                float v = acc[i][j][r] + bb;
                acc[i][j][r] = 0.5f * v * (1.0f + erff(v * 0.70710678118654752f));
            }
    }

    // w2 rows for this lane's 4 n-columns
    float w2r[4][8];
    #pragma unroll
    for (int j = 0; j < 4; j++) {
        const float4* p = (const float4*)(w2 + (size_t)(n0g + wn * 64 + j * 16 + l15) * NEXP);
        float4 u = p[0], v = p[1];
        w2r[j][0] = u.x; w2r[j][1] = u.y; w2r[j][2] = u.z; w2r[j][3] = u.w;
        w2r[j][4] = v.x; w2r[j][5] = v.y; w2r[j][6] = v.z; w2r[j][7] = v.w;
    }

    const int sl = bn * 2 + wn;  // partial slice: covers n in [sl*64, sl*64+64)
    #pragma unroll
    for (int e = 0; e < NEXP; e++) {
        float p[4][4];
        #pragma unroll
        for (int i = 0; i < 4; i++)
            #pragma unroll
            for (int r = 0; r < 4; r++) {
                float s = 0.f;
                #pragma unroll
                for (int j = 0; j < 4; j++) s += acc[i][j][r] * w2r[j][e];
                p[i][r] = s;
            }
        #pragma unroll
        for (int off = 1; off < 16; off <<= 1)
            #pragma unroll
            for (int i = 0; i < 4; i++)
                #pragma unroll
                for (int r = 0; r < 4; r++)
                    p[i][r] += __shfl_xor(p[i][r], off);
        if (l15 == 0) {
            #pragma unroll
            for (int i = 0; i < 4; i++)
                #pragma unroll
                for (int r = 0; r < 4; r++) {
                    int m = m0 + wm * 64 + i * 16 + q * 4 + r;
                    part[(size_t)sl * (MTOK * NEXP) + (size_t)m * NEXP + e] = p[i][r];
                }
        }
    }
}

// --- Kernel 2: deterministic sum of 32 slices -> logits, top-2, softmax ---
__global__ __launch_bounds__(256) void router_topk(
    const float* __restrict__ part, const float* __restrict__ b2,
    float* __restrict__ out, float* __restrict__ gu, int* __restrict__ gc)
{
    const int t = blockIdx.x * 256 + threadIdx.x;

    float logit[8];
    #pragma unroll
    for (int e = 0; e < 8; e++) logit[e] = b2[e];
    #pragma unroll
    for (int j = 0; j < NSLC; j++) {
        const float4* p4 = (const float4*)(part + (size_t)j * (MTOK * NEXP) + (size_t)t * NEXP);
        float4 u = p4[0], v = p4[1];
        logit[0] += u.x; logit[1] += u.y; logit[2] += u.z; logit[3] += u.w;
        logit[4] += v.x; logit[5] += v.y; logit[6] += v.z; logit[7] += v.w;
    }

    int i1 = 0; float v1 = logit[0];
    #pragma unroll
    for (int e = 1; e < 8; e++) { if (logit[e] > v1) { v1 = logit[e]; i1 = e; } }
    int i2 = -1; float v2 = -INFINITY;
    #pragma unroll
    for (int e = 0; e < 8; e++) {
        if (e != i1 && logit[e] > v2) { v2 = logit[e]; i2 = e; }
    }
    float ex = expf(v2 - v1);
    float inv = 1.0f / (1.0f + ex);
    float wa = inv, wb = ex * inv;

    float4* o = (float4*)(out + (size_t)t * NEXP);
    o[0] = make_float4(logit[0], logit[1], logit[2], logit[3]);
    o[1] = make_float4(logit[4], logit[5], logit[6], logit[7]);

    float mk[8];
    #pragma unroll
    for (int e = 0; e < 8; e++) mk[e] = 0.0f;
    mk[i1] = wa; mk[i2] = wb;
    float4* om = (float4*)(out + (size_t)(MTOK * NEXP) + (size_t)t * NEXP);
    om[0] = make_float4(mk[0], mk[1], mk[2], mk[3]);
    om[1] = make_float4(mk[4], mk[5], mk[6], mk[7]);

    __shared__ float us[8];
    __shared__ int cs;
    if (threadIdx.x < 8) us[threadIdx.x] = 0.0f;
    if (threadIdx.x == 0) cs = 0;
    __syncthreads();
    atomicAdd(&us[i1], wa);
    atomicAdd(&us[i2], wb);
    int cnt = (wa > 0.0f ? 1 : 0) + (wb > 0.0f ? 1 : 0);
    atomicAdd(&cs, cnt);
    __syncthreads();
    if (threadIdx.x < 8) atomicAdd(&gu[threadIdx.x], us[threadIdx.x]);
    if (threadIdx.x == 0) atomicAdd(gc, cs);
}

// --- Kernel 3: finalize losses + normalized usage ---
__global__ void router_final(const float* __restrict__ gu, const int* __restrict__ gc,
                             float* __restrict__ out)
{
    if (blockIdx.x == 0 && threadIdx.x == 0) {
        float u[8]; float tot = 0.0f;
        for (int e = 0; e < 8; e++) { u[e] = gu[e]; tot += u[e]; }
        float lb = 0.0f;
        for (int e = 0; e < 8; e++) {
            float un = u[e] / tot;
            out[2 * MTOK * NEXP + 1 + e] = un;
            float d = un - 0.125f;
            lb += d * d;
        }
        lb *= (1.0f / 8.0f);
        float sp = ((float)(*gc) / (float)MTOK) * 0.5f;
        out[2 * MTOK * NEXP] = lb + 0.1f * sp;
    }
}

extern "C" void kernel_launch(void* const* d_in, const int* in_sizes, int n_in,
                              void* d_out, int out_size, void* d_ws, size_t ws_size,
                              hipStream_t stream) {
    const float* x  = (const float*)d_in[0];
    const float* w1 = (const float*)d_in[1];
    const float* b1 = (const float*)d_in[2];
    const float* w2 = (const float*)d_in[3];
    const float* b2 = (const float*)d_in[4];
    float* out = (float*)d_out;

    unsigned short* af = (unsigned short*)d_ws;            // 1024*32768*2 B = 64 MiB
    unsigned short* wf = af + (size_t)1024 * 32768;        // 8 MiB
    float* part = (float*)(wf + (size_t)128 * 32 * 1024);  // 16 MiB
    float* gu = part + (size_t)NSLC * MTOK * NEXP;
    int* gc = (int*)(gu + 8);

    static bool attr_done = false;
    if (!attr_done) {
        hipFuncSetAttribute((const void*)gemm1_mfma,
                            hipFuncAttributeMaxDynamicSharedMemorySize, LDS_BYTES);
        attr_done = true;
    }

    hipMemsetAsync(gu, 0, 64, stream);

    cvt_x<<<1024, 256, 0, stream>>>(x, af);
    cvt_w1f<<<dim3(FDIM / 32, HDIM / 32), 256, 0, stream>>>(w1, wf);
    gemm1_mfma<<<1024, 512, LDS_BYTES, stream>>>(af, wf, b1, w2, part);
    router_topk<<<MTOK / 256, 256, 0, stream>>>(part, b2, out, gu, gc);
    router_final<<<1, 64, 0, stream>>>(gu, gc, out);
}

// Round 7
// 341.521 us; speedup vs baseline: 1.2361x; 1.0591x over previous
//
#include <hip/hip_runtime.h>
#include <math.h>

#define HDIM 1024
#define FDIM 2048   // 2H
#define NEXP 8
#define MTOK 16384  // 8*2048 tokens
#define NSLC 32     // partial-logit slices: 16 n-blocks x 2 wn-waves
#define BM 128
#define BN 128

typedef __attribute__((ext_vector_type(8))) short bf16x8;   // 8 bf16 = 4 VGPRs
typedef __attribute__((ext_vector_type(4))) float f32x4;

__device__ inline unsigned short f2bf_rne(float f) {
    unsigned int u = __float_as_uint(f);
    u = (u + 0x7FFFu + ((u >> 16) & 1u)) >> 16;
    return (unsigned short)u;
}
__device__ inline float bf2f(unsigned short h) {
    unsigned int u = ((unsigned int)h) << 16;
    return __uint_as_float(u);
}

// --- Kernel A: x fp32 -> FRAGMENT-MAJOR split bf16 af ---
// af[mt][kb][hl][lane][j]: mt=m>>4 (1024), kb=k>>5 (32), hl in {h,l},
// lane = ((k>>3)&3)*16 + (m&15), j = k&7. Per (mt,kb): 1024 shorts (2 KB).
// A wave's A-fragment load in the GEMM = base + lane*16B (coalesced 1 KB).
__global__ __launch_bounds__(256) void cvt_x(const float* __restrict__ x,
                                             unsigned short* __restrict__ af)
{
    __shared__ unsigned short hs[16384];  // 32 KB  [kb][m][q][j]
    __shared__ unsigned short ls[16384];  // 32 KB
    const int mt = blockIdx.x;            // 0..1023
    const float* src = x + (size_t)mt * 16384;
    const int m = threadIdx.x & 15;
    const int kseg = threadIdx.x >> 4;    // 0..15

    #pragma unroll
    for (int c = 0; c < 8; c++) {
        int k = c * 128 + kseg * 8;
        float v[8];
        *(float4*)(v)     = *(const float4*)(src + m * 1024 + k);
        *(float4*)(v + 4) = *(const float4*)(src + m * 1024 + k + 4);
        union { unsigned short u[8]; uint4 q; } oh, ol;
        #pragma unroll
        for (int j = 0; j < 8; j++) {
            unsigned short h = f2bf_rne(v[j]);
            oh.u[j] = h;
            ol.u[j] = f2bf_rne(v[j] - bf2f(h));
        }
        int kb = k >> 5, q = (k >> 3) & 3;
        int o = kb * 512 + m * 32 + q * 8;
        *(uint4*)(hs + o) = oh.q;
        *(uint4*)(ls + o) = ol.q;
    }
    __syncthreads();
    unsigned short* dst = af + (size_t)mt * 32768;
    #pragma unroll
    for (int c = 0; c < 16; c++) {
        int f = c * 2048 + threadIdx.x * 8;       // flat out index (shorts)
        int kb = f >> 10, half = (f >> 9) & 1, idx = f & 511;
        int q = idx >> 7, mm = (idx >> 3) & 15;
        const unsigned short* s = (half ? ls : hs) + kb * 512 + mm * 32 + q * 8;
        *(uint4*)(dst + f) = *(const uint4*)s;
    }
}

// --- Kernel B: w1 [K][N] fp32 -> FRAGMENT-MAJOR split bf16 wf ---
__global__ __launch_bounds__(256) void cvt_w1f(const float* __restrict__ w1,
                                               unsigned short* __restrict__ wf)
{
    __shared__ float t[32][33];
    int n0 = blockIdx.x * 32;   // over FDIM
    int k0 = blockIdx.y * 32;   // over HDIM
    int lx = threadIdx.x & 31, ly = threadIdx.x >> 5;  // 32 x 8
    #pragma unroll
    for (int r = 0; r < 32; r += 8)
        t[ly + r][lx] = w1[(size_t)(k0 + ly + r) * FDIM + n0 + lx];
    __syncthreads();
    #pragma unroll
    for (int r = 0; r < 32; r += 8) {
        float v = t[lx][ly + r];
        unsigned short h = f2bf_rne(v);
        unsigned short l = f2bf_rne(v - bf2f(h));
        int n = n0 + ly + r, k = k0 + lx;
        size_t base = (size_t)((n >> 4) * 32 + (k >> 5)) * 1024;
        int lj = (((k >> 3) & 3) * 16 + (n & 15)) * 8 + (k & 7);
        wf[base + lj] = h;
        wf[base + 512 + lj] = l;
    }
}

// --- Kernel C: split-bf16 MFMA GEMM1 — NO LDS, NO BARRIERS in K-loop. ---
// Both operands fragment-major in global (L1/L2-hit); register double-buffer
// one kb ahead -> compiler emits fine-grained vmcnt, MFMA/load interleave.
// 4 waves, 2x2 of 64x64 tiles; acc += ah*bh + ah*bl + al*bh per kb.
// Measured optimum of this design family (227.8 us): delivery-bound at the
// register wall (64 AGPR acc + ~96 frag VGPRs -> 2 waves/SIMD; r3-r5 showed
// any expansion spills, r1/r2/r6 showed LDS staging loses to barrier lockstep).
__global__ __launch_bounds__(256, 2) void gemm1_mfma(
    const unsigned short* __restrict__ af, const unsigned short* __restrict__ wf,
    const float* __restrict__ b1, const float* __restrict__ w2,
    float* __restrict__ part)
{
    const int tid  = threadIdx.x;
    const int lane = tid & 63;
    const int l15  = lane & 15;
    const int q    = lane >> 4;
    const int wave = tid >> 6;
    const int wm   = wave & 1;
    const int wn   = wave >> 1;

    // XCD-aware swizzle: same-XCD sequences walk 4-bm strips x 16 bn so each
    // XCD's L2 holds its A strip (~2 MB) + current B tile; A read once/XCD.
    const int id = blockIdx.x;          // 0..2047 linear
    const int xcd = id & 7, seq = id >> 3;
    const int strip = seq >> 6;         // 0..3
    const int bn = (seq >> 2) & 15;
    const int bmo = seq & 3;
    const int bm = strip * 32 + xcd * 4 + bmo;
    const int m0 = bm * BM, n0 = bn * BN;

    // fragment pointers: frag i -> mt/nt tile, lane offset fixed
    const unsigned short* apt[4];
    const unsigned short* bpt[4];
    #pragma unroll
    for (int i = 0; i < 4; i++) {
        apt[i] = af + ((size_t)(bm * 8 + wm * 4 + i) * 32) * 1024 + lane * 8;
        bpt[i] = wf + ((size_t)(bn * 8 + wn * 4 + i) * 32) * 1024 + lane * 8;
    }

    f32x4 acc[4][4];
    #pragma unroll
    for (int i = 0; i < 4; i++)
        #pragma unroll
        for (int j = 0; j < 4; j++) acc[i][j] = (f32x4){0.f, 0.f, 0.f, 0.f};

    bf16x8 Ah0[4], Al0[4], Bh0[4], Bl0[4];
    bf16x8 Ah1[4], Al1[4], Bh1[4], Bl1[4];

    // kb = 0 into buf0
    #pragma unroll
    for (int i = 0; i < 4; i++) {
        Ah0[i] = *(const bf16x8*)(apt[i]);
        Al0[i] = *(const bf16x8*)(apt[i] + 512);
        Bh0[i] = *(const bf16x8*)(bpt[i]);
        Bl0[i] = *(const bf16x8*)(bpt[i] + 512);
    }

    #pragma unroll 1
    for (int t = 0; t < 32; t += 2) {
        // prefetch kb = t+1 into buf1 (window offset 1024 shorts)
        #pragma unroll
        for (int i = 0; i < 4; i++) {
            Ah1[i] = *(const bf16x8*)(apt[i] + 1024);
            Al1[i] = *(const bf16x8*)(apt[i] + 1536);
            Bh1[i] = *(const bf16x8*)(bpt[i] + 1024);
            Bl1[i] = *(const bf16x8*)(bpt[i] + 1536);
        }
        // compute kb = t on buf0
        #pragma unroll
        for (int i = 0; i < 4; i++)
            #pragma unroll
            for (int j = 0; j < 4; j++) {
                acc[i][j] = __builtin_amdgcn_mfma_f32_16x16x32_bf16(
                    Ah0[i], Bh0[j], acc[i][j], 0, 0, 0);
                acc[i][j] = __builtin_amdgcn_mfma_f32_16x16x32_bf16(
                    Ah0[i], Bl0[j], acc[i][j], 0, 0, 0);
                acc[i][j] = __builtin_amdgcn_mfma_f32_16x16x32_bf16(
                    Al0[i], Bh0[j], acc[i][j], 0, 0, 0);
            }
        // advance to next window, prefetch kb = t+2 into buf0
        #pragma unroll
        for (int i = 0; i < 4; i++) { apt[i] += 2048; bpt[i] += 2048; }
        if (t + 2 < 32) {
            #pragma unroll
            for (int i = 0; i < 4; i++) {
                Ah0[i] = *(const bf16x8*)(apt[i]);
                Al0[i] = *(const bf16x8*)(apt[i] + 512);
                Bh0[i] = *(const bf16x8*)(bpt[i]);
                Bl0[i] = *(const bf16x8*)(bpt[i] + 512);
            }
        }
        // compute kb = t+1 on buf1
        #pragma unroll
        for (int i = 0; i < 4; i++)
            #pragma unroll
            for (int j = 0; j < 4; j++) {
                acc[i][j] = __builtin_amdgcn_mfma_f32_16x16x32_bf16(
                    Ah1[i], Bh1[j], acc[i][j], 0, 0, 0);
                acc[i][j] = __builtin_amdgcn_mfma_f32_16x16x32_bf16(
                    Ah1[i], Bl1[j], acc[i][j], 0, 0, 0);
                acc[i][j] = __builtin_amdgcn_mfma_f32_16x16x32_bf16(
                    Al1[i], Bh1[j], acc[i][j], 0, 0, 0);
            }
    }

    // --- epilogue: bias + exact GELU (C/D: col=lane&15 -> n, row=q*4+r -> m) ---
    #pragma unroll
    for (int j = 0; j < 4; j++) {
        int n = n0 + wn * 64 + j * 16 + l15;
        float bb = b1[n];
        #pragma unroll
        for (int i = 0; i < 4; i++)
            #pragma unroll
            for (int r = 0; r < 4; r++) {
                float v = acc[i][j][r] + bb;
                acc[i][j][r] = 0.5f * v * (1.0f + erff(v * 0.70710678118654752f));
            }
    }

    // w2 rows for this lane's 4 n-columns
    float w2r[4][8];
    #pragma unroll
    for (int j = 0; j < 4; j++) {
        const float4* p = (const float4*)(w2 + (size_t)(n0 + wn * 64 + j * 16 + l15) * NEXP);
        float4 u = p[0], v = p[1];
        w2r[j][0] = u.x; w2r[j][1] = u.y; w2r[j][2] = u.z; w2r[j][3] = u.w;
        w2r[j][4] = v.x; w2r[j][5] = v.y; w2r[j][6] = v.z; w2r[j][7] = v.w;
    }

    const int sl = bn * 2 + wn;  // partial slice (deterministic)
    #pragma unroll
    for (int e = 0; e < NEXP; e++) {
        float p[4][4];
        #pragma unroll
        for (int i = 0; i < 4; i++)
            #pragma unroll
            for (int r = 0; r < 4; r++) {
                float s = 0.f;
                #pragma unroll
                for (int j = 0; j < 4; j++) s += acc[i][j][r] * w2r[j][e];
                p[i][r] = s;
            }
        #pragma unroll
        for (int off = 1; off < 16; off <<= 1)
            #pragma unroll
            for (int i = 0; i < 4; i++)
                #pragma unroll
                for (int r = 0; r < 4; r++)
                    p[i][r] += __shfl_xor(p[i][r], off);
        if (l15 == 0) {
            #pragma unroll
            for (int i = 0; i < 4; i++)
                #pragma unroll
                for (int r = 0; r < 4; r++) {
                    int m = m0 + wm * 64 + i * 16 + q * 4 + r;
                    part[(size_t)sl * (MTOK * NEXP) + (size_t)m * NEXP + e] = p[i][r];
                }
        }
    }
}

// --- Kernel 2: deterministic sum of 32 slices -> logits, top-2, softmax ---
__global__ __launch_bounds__(256) void router_topk(
    const float* __restrict__ part, const float* __restrict__ b2,
    float* __restrict__ out, float* __restrict__ gu, int* __restrict__ gc)
{
    const int t = blockIdx.x * 256 + threadIdx.x;

    float logit[8];
    #pragma unroll
    for (int e = 0; e < 8; e++) logit[e] = b2[e];
    #pragma unroll
    for (int j = 0; j < NSLC; j++) {
        const float4* p4 = (const float4*)(part + (size_t)j * (MTOK * NEXP) + (size_t)t * NEXP);
        float4 u = p4[0], v = p4[1];
        logit[0] += u.x; logit[1] += u.y; logit[2] += u.z; logit[3] += u.w;
        logit[4] += v.x; logit[5] += v.y; logit[6] += v.z; logit[7] += v.w;
    }

    int i1 = 0; float v1 = logit[0];
    #pragma unroll
    for (int e = 1; e < 8; e++) { if (logit[e] > v1) { v1 = logit[e]; i1 = e; } }
    int i2 = -1; float v2 = -INFINITY;
    #pragma unroll
    for (int e = 0; e < 8; e++) {
        if (e != i1 && logit[e] > v2) { v2 = logit[e]; i2 = e; }
    }
    float ex = expf(v2 - v1);
    float inv = 1.0f / (1.0f + ex);
    float wa = inv, wb = ex * inv;

    float4* o = (float4*)(out + (size_t)t * NEXP);
    o[0] = make_float4(logit[0], logit[1], logit[2], logit[3]);
    o[1] = make_float4(logit[4], logit[5], logit[6], logit[7]);

    float mk[8];
    #pragma unroll
    for (int e = 0; e < 8; e++) mk[e] = 0.0f;
    mk[i1] = wa; mk[i2] = wb;
    float4* om = (float4*)(out + (size_t)(MTOK * NEXP) + (size_t)t * NEXP);
    om[0] = make_float4(mk[0], mk[1], mk[2], mk[3]);
    om[1] = make_float4(mk[4], mk[5], mk[6], mk[7]);

    __shared__ float us[8];
    __shared__ int cs;
    if (threadIdx.x < 8) us[threadIdx.x] = 0.0f;
    if (threadIdx.x == 0) cs = 0;
    __syncthreads();
    atomicAdd(&us[i1], wa);
    atomicAdd(&us[i2], wb);
    int cnt = (wa > 0.0f ? 1 : 0) + (wb > 0.0f ? 1 : 0);
    atomicAdd(&cs, cnt);
    __syncthreads();
    if (threadIdx.x < 8) atomicAdd(&gu[threadIdx.x], us[threadIdx.x]);
    if (threadIdx.x == 0) atomicAdd(gc, cs);
}

// --- Kernel 3: finalize losses + normalized usage ---
__global__ void router_final(const float* __restrict__ gu, const int* __restrict__ gc,
                             float* __restrict__ out)
{
    if (blockIdx.x == 0 && threadIdx.x == 0) {
        float u[8]; float tot = 0.0f;
        for (int e = 0; e < 8; e++) { u[e] = gu[e]; tot += u[e]; }
        float lb = 0.0f;
        for (int e = 0; e < 8; e++) {
            float un = u[e] / tot;
            out[2 * MTOK * NEXP + 1 + e] = un;
            float d = un - 0.125f;
            lb += d * d;
        }
        lb *= (1.0f / 8.0f);
        float sp = ((float)(*gc) / (float)MTOK) * 0.5f;
        out[2 * MTOK * NEXP] = lb + 0.1f * sp;
    }
}

extern "C" void kernel_launch(void* const* d_in, const int* in_sizes, int n_in,
                              void* d_out, int out_size, void* d_ws, size_t ws_size,
                              hipStream_t stream) {
    const float* x  = (const float*)d_in[0];
    const float* w1 = (const float*)d_in[1];
    const float* b1 = (const float*)d_in[2];
    const float* w2 = (const float*)d_in[3];
    const float* b2 = (const float*)d_in[4];
    float* out = (float*)d_out;

    unsigned short* af = (unsigned short*)d_ws;            // 1024*32768*2 B = 64 MiB
    unsigned short* wf = af + (size_t)1024 * 32768;        // 8 MiB
    float* part = (float*)(wf + (size_t)128 * 32 * 1024);  // 16 MiB
    float* gu = part + (size_t)NSLC * MTOK * NEXP;
    int* gc = (int*)(gu + 8);

    hipMemsetAsync(gu, 0, 64, stream);

    cvt_x<<<1024, 256, 0, stream>>>(x, af);
    cvt_w1f<<<dim3(FDIM / 32, HDIM / 32), 256, 0, stream>>>(w1, wf);
    gemm1_mfma<<<2048, 256, 0, stream>>>(af, wf, b1, w2, part);
    router_topk<<<MTOK / 256, 256, 0, stream>>>(part, b2, out, gu, gc);
    router_final<<<1, 64, 0, stream>>>(gu, gc, out);
}